// Round 9
// baseline (216.842 us; speedup 1.0000x reference)
//
#include <hip/hip_runtime.h>
#include <math.h>

#define LENGTH 4096
#define BATCH  4096
#define CHUNK  8       // timesteps per thread
#define NTHR   512     // threads per block; NTHR*CHUNK == LENGTH (one row per iter)
#define NWAVE  (NTHR / 64)
#define GRIDB  1024    // persistent blocks (4 per CU)
#define RPB    (BATCH / GRIDB)   // 4 rows per block

typedef float vf4 __attribute__((ext_vector_type(4)));

// max-plus 2x2 compose: D = A (x) B, D[k][l] = max_m A[k][m] + B[m][l]
__device__ __forceinline__ void mp_compose(
    float a00, float a01, float a10, float a11,
    float b00, float b01, float b10, float b11,
    float& d00, float& d01, float& d10, float& d11) {
  d00 = fmaxf(a00 + b00, a01 + b10);
  d01 = fmaxf(a00 + b01, a01 + b11);
  d10 = fmaxf(a10 + b00, a11 + b10);
  d11 = fmaxf(a10 + b01, a11 + b11);
}

// F <- (S (x) D_u) (x) F
__device__ __forceinline__ void mp_step(
    float& f00, float& f01, float& f10, float& f11, float ui, float q) {
  float a0l0 = f00 - ui, a1l0 = f10 + ui;
  float a0l1 = f01 - ui, a1l1 = f11 + ui;
  float n00 = fmaxf(a0l0 + q, a1l0 - q);
  float n10 = fmaxf(a0l0 - q, a1l0 + q);
  float n01 = fmaxf(a0l1 + q, a1l1 - q);
  float n11 = fmaxf(a0l1 - q, a1l1 + q);
  f00 = n00; f01 = n01; f10 = n10; f11 = n11;
}

__global__ __launch_bounds__(NTHR, 8) void chain_bp_kernel(
    const float* __restrict__ jp, const float* __restrict__ bp,
    const int* __restrict__ obs, float* __restrict__ out) {
  const int bid  = blockIdx.x;
  const int tid  = threadIdx.x;
  const int lane = tid & 63;
  const int wv   = tid >> 6;

  // Potentials pre-scaled by log2(e): epilogue uses raw v_exp_f32 (2^x).
  const float LOG2E = 1.44269504088896f;
  const float j  = jp[0];
  const float q  = 0.25f * j * LOG2E;
  const float u0 = 0.5f * bp[0] * LOG2E;
  const float u1 = 0.5f * bp[1] * LOG2E;
  const float wb = -fabsf(q);              // 0vec == S (x) (wb,wb)

  __shared__ vf4 lut4s[16];
  __shared__ vf4 lut8[256];
  __shared__ float smp[2][NWAVE][4];       // double-buffered stitch scratch
  __shared__ float sms[2][NWAVE][4];

  // ---- LUT: built ONCE per persistent block ----
  if (tid < 16) {
    float ua = (tid & 1) ? u1 : u0;
    float f00 = -ua + q, f01 = ua - q, f10 = -ua - q, f11 = ua + q;
#pragma unroll
    for (int k = 1; k < 4; ++k)
      mp_step(f00, f01, f10, f11, ((tid >> k) & 1) ? u1 : u0, q);
    lut4s[tid] = (vf4){f00, f01, f10, f11};
  }
  __syncthreads();
  if (tid < 256) {
    vf4 a = lut4s[tid >> 4], c = lut4s[tid & 15];
    float d00, d01, d10, d11;
    mp_compose(a[0], a[1], a[2], a[3], c[0], c[1], c[2], c[3], d00, d01, d10, d11);
    lut8[tid] = (vf4){d00, d01, d10, d11};
  }
  __syncthreads();

  const int t0 = tid * CHUNK;
  // preload first row's observations
  const int4* op = reinterpret_cast<const int4*>(obs + (size_t)bid * LENGTH + t0);
  int4 o0 = op[0], o1 = op[1];

#pragma unroll
  for (int r = 0; r < RPB; ++r) {
    const int row = bid + r * GRIDB;
    // ---- prefetch NEXT row's observations (in flight during this row) ----
    int4 n0, n1;
    if (r + 1 < RPB) {
      const int4* np = reinterpret_cast<const int4*>(
          obs + (size_t)(row + GRIDB) * LENGTH + t0);
      n0 = np[0]; n1 = np[1];
    }

    // ---- unpack current row ----
    float u[CHUNK];
    u[0]=o0.x?u1:u0; u[1]=o0.y?u1:u0; u[2]=o0.z?u1:u0; u[3]=o0.w?u1:u0;
    u[4]=o1.x?u1:u0; u[5]=o1.y?u1:u0; u[6]=o1.z?u1:u0; u[7]=o1.w?u1:u0;
    int idx = o0.x | (o0.y<<1) | (o0.z<<2) | (o0.w<<3)
            | (o1.x<<4) | (o1.y<<5) | (o1.z<<6) | (o1.w<<7);

    vf4 Fm = lut8[idx];
    float f00 = Fm[0], f01 = Fm[1], f10 = Fm[2], f11 = Fm[3];

    // ---- interleaved wave scans: prefix X over F, suffix Y over F^T ----
    float x00 = f00, x01 = f01, x10 = f10, x11 = f11;
    float y00 = f00, y01 = f10, y10 = f01, y11 = f11;  // transpose
#pragma unroll
    for (int d = 1; d < 64; d <<= 1) {
      float px00 = __shfl_up(x00, d), px01 = __shfl_up(x01, d);
      float px10 = __shfl_up(x10, d), px11 = __shfl_up(x11, d);
      float py00 = __shfl_down(y00, d), py01 = __shfl_down(y01, d);
      float py10 = __shfl_down(y10, d), py11 = __shfl_down(y11, d);
      if (lane >= d) {
        float m00, m01, m10, m11;
        mp_compose(x00, x01, x10, x11, px00, px01, px10, px11, m00, m01, m10, m11);
        x00 = m00; x01 = m01; x10 = m10; x11 = m11;
      }
      if (lane + d < 64) {
        float m00, m01, m10, m11;
        mp_compose(y00, y01, y10, y11, py00, py01, py10, py11, m00, m01, m10, m11);
        y00 = m00; y01 = m01; y10 = m10; y11 = m11;
      }
    }

    // ---- cross-wave stitch (double-buffered; ONE barrier per row) ----
    const int pb = r & 1;
    if (lane == 63) {
      smp[pb][wv][0] = x00; smp[pb][wv][1] = x01;
      smp[pb][wv][2] = x10; smp[pb][wv][3] = x11;
    }
    if (lane == 0) {
      sms[pb][wv][0] = y00; sms[pb][wv][1] = y01;
      sms[pb][wv][2] = y10; sms[pb][wv][3] = y11;
    }
    __syncthreads();

    float fh0 = 0.f, fh1 = 0.f;
    for (int k = 0; k < wv; ++k) {
      float m0 = fmaxf(smp[pb][k][0] + fh0, smp[pb][k][1] + fh1);
      float m1 = fmaxf(smp[pb][k][2] + fh0, smp[pb][k][3] + fh1);
      fh0 = m0; fh1 = m1;
    }
    float wt0 = wb, wt1 = wb;
    for (int k = NWAVE - 1; k > wv; --k) {
      float m0 = fmaxf(sms[pb][k][0] + wt0, sms[pb][k][1] + wt1);
      float m1 = fmaxf(sms[pb][k][2] + wt0, sms[pb][k][3] + wt1);
      wt0 = m0; wt1 = m1;
    }

    // fwd boundary: z_c = X_c (x) fhead; f_in = z_{c-1}
    float z0 = fmaxf(x00 + fh0, x01 + fh1);
    float z1 = fmaxf(x10 + fh0, x11 + fh1);
    float zp0 = __shfl_up(z0, 1), zp1 = __shfl_up(z1, 1);
    float fi0 = (lane == 0) ? fh0 : zp0;
    float fi1 = (lane == 0) ? fh1 : zp1;

    // bwd boundary: y_c = Y_c (x) wtail = w_{c-1}; w_c from lane+1
    float yv0 = fmaxf(y00 + wt0, y01 + wt1);
    float yv1 = fmaxf(y10 + wt0, y11 + wt1);
    float yn0 = __shfl_down(yv0, 1), yn1 = __shfl_down(yv1, 1);
    float wc0 = (lane == 63) ? wt0 : yn0;
    float wc1 = (lane == 63) ? wt1 : yn1;
    float g0 = fmaxf(q + wc0, -q + wc1);
    float g1 = fmaxf(-q + wc0, q + wc1);

    // ---- in-chunk backward sweep ----
    float b0[CHUNK], b1[CHUNK];
    b0[CHUNK - 1] = g0; b1[CHUNK - 1] = g1;
#pragma unroll
    for (int i = CHUNK - 1; i > 0; --i) {
      float a0 = b0[i] - u[i], a1 = b1[i] + u[i];
      b0[i - 1] = fmaxf(a0 + q, a1 - q);
      b1[i - 1] = fmaxf(a0 - q, a1 + q);
    }

    // ---- forward sweep + beliefs (exp2); 4 adjacent 16B stores ----
    float fw0 = fi0, fw1 = fi1;
    vf4 p0lo, p0hi, p1lo, p1hi;
#pragma unroll
    for (int i = 0; i < CHUNK; ++i) {
      float ui = u[i];
      float e0 = __builtin_amdgcn_exp2f(-ui + fw0 + b0[i]);
      float e1 = __builtin_amdgcn_exp2f( ui + fw1 + b1[i]);
      if (i < 4) { p0lo[i] = e0; p1lo[i] = e1; }
      else       { p0hi[i - 4] = e0; p1hi[i - 4] = e1; }
      float a0 = fw0 - ui, a1 = fw1 + ui;
      fw0 = fmaxf(a0 + q, a1 - q);
      fw1 = fmaxf(a0 - q, a1 + q);
    }
    float* outp = out + (size_t)row * (2 * LENGTH) + t0;
    *reinterpret_cast<vf4*>(outp)              = p0lo;
    *reinterpret_cast<vf4*>(outp + 4)          = p0hi;
    *reinterpret_cast<vf4*>(outp + LENGTH)     = p1lo;
    *reinterpret_cast<vf4*>(outp + LENGTH + 4) = p1hi;

    // rotate prefetched row in
    o0 = n0; o1 = n1;
  }
}

extern "C" void kernel_launch(void* const* d_in, const int* in_sizes, int n_in,
                              void* d_out, int out_size, void* d_ws, size_t ws_size,
                              hipStream_t stream) {
  const float* jp  = (const float*)d_in[0];   // scalar j
  const float* bp  = (const float*)d_in[1];   // b[2]
  const int*   obs = (const int*)d_in[2];     // [BATCH, LENGTH] int32
  float* out = (float*)d_out;                 // [BATCH, 2, LENGTH] fp32

  chain_bp_kernel<<<GRIDB, NTHR, 0, stream>>>(jp, bp, obs, out);
}

// Round 10
// 195.311 us; speedup vs baseline: 1.1102x; 1.1102x over previous
//
#include <hip/hip_runtime.h>
#include <math.h>

#define LENGTH 4096
#define BATCH  4096
#define CHUNK  4       // timesteps per thread
#define NTHR   1024    // threads per block; NTHR*CHUNK == LENGTH (one block per row)
#define NWAVE  (NTHR / 64)

typedef float vf4 __attribute__((ext_vector_type(4)));

// max-plus 2x2 compose: D = A (x) B, D[k][l] = max_m A[k][m] + B[m][l]
__device__ __forceinline__ void mp_compose(
    float a00, float a01, float a10, float a11,
    float b00, float b01, float b10, float b11,
    float& d00, float& d01, float& d10, float& d11) {
  d00 = fmaxf(a00 + b00, a01 + b10);
  d01 = fmaxf(a00 + b01, a01 + b11);
  d10 = fmaxf(a10 + b00, a11 + b10);
  d11 = fmaxf(a10 + b01, a11 + b11);
}

// F <- (S (x) D_u) (x) F     (one timestep applied on the left)
__device__ __forceinline__ void mp_step(
    float& f00, float& f01, float& f10, float& f11, float ui, float q) {
  float a0l0 = f00 - ui, a1l0 = f10 + ui;
  float a0l1 = f01 - ui, a1l1 = f11 + ui;
  float n00 = fmaxf(a0l0 + q, a1l0 - q);
  float n10 = fmaxf(a0l0 - q, a1l0 + q);
  float n01 = fmaxf(a0l1 + q, a1l1 - q);
  float n11 = fmaxf(a0l1 - q, a1l1 + q);
  f00 = n00; f01 = n01; f10 = n10; f11 = n11;
}

__global__ __launch_bounds__(NTHR, 8) void chain_bp_kernel(
    const float* __restrict__ jp, const float* __restrict__ bp,
    const int* __restrict__ obs, float* __restrict__ out) {
  const int row  = blockIdx.x;
  const int tid  = threadIdx.x;
  const int lane = tid & 63;
  const int wv   = tid >> 6;

  // Potentials pre-scaled by log2(e): epilogue uses raw v_exp_f32 (2^x).
  const float LOG2E = 1.44269504088896f;
  const float j  = jp[0];
  const float q  = 0.25f * j * LOG2E;      // log2 psi diag; off-diag = -q
  const float u0 = 0.5f * bp[0] * LOG2E;   // log2 phi[o=0][s=1] ; s=0 is -u
  const float u1 = 0.5f * bp[1] * LOG2E;
  const float wb = -fabsf(q);              // 0vec == S (x) (wb,wb)

  __shared__ float smp[NWAVE][4];  // per-wave full prefix matrix
  __shared__ float sms[NWAVE][4];  // per-wave full suffix matrix

  // ---- load this thread's 4 observations (one int4, fully coalesced) ----
  const int t0 = tid * CHUNK;
  const int4* op = reinterpret_cast<const int4*>(obs + (size_t)row * LENGTH + t0);
  int4 o = op[0];
  float u[CHUNK];
  u[0] = o.x ? u1 : u0;
  u[1] = o.y ? u1 : u0;
  u[2] = o.z ? u1 : u0;
  u[3] = o.w ? u1 : u0;

  // ---- build 4-step chunk matrix F directly (~52 VALU, no LUT/barriers) ----
  float f00 = -u[0] + q, f01 = u[0] - q, f10 = -u[0] - q, f11 = u[0] + q;
  mp_step(f00, f01, f10, f11, u[1], q);
  mp_step(f00, f01, f10, f11, u[2], q);
  mp_step(f00, f01, f10, f11, u[3], q);

  // ---- interleaved wave scans: prefix X over F, suffix Y over F^T ----
  float x00 = f00, x01 = f01, x10 = f10, x11 = f11;
  float y00 = f00, y01 = f10, y10 = f01, y11 = f11;  // transpose
#pragma unroll
  for (int d = 1; d < 64; d <<= 1) {
    float px00 = __shfl_up(x00, d), px01 = __shfl_up(x01, d);
    float px10 = __shfl_up(x10, d), px11 = __shfl_up(x11, d);
    float py00 = __shfl_down(y00, d), py01 = __shfl_down(y01, d);
    float py10 = __shfl_down(y10, d), py11 = __shfl_down(y11, d);
    if (lane >= d) {
      float m00, m01, m10, m11;
      mp_compose(x00, x01, x10, x11, px00, px01, px10, px11, m00, m01, m10, m11);
      x00 = m00; x01 = m01; x10 = m10; x11 = m11;
    }
    if (lane + d < 64) {
      float m00, m01, m10, m11;
      mp_compose(y00, y01, y10, y11, py00, py01, py10, py11, m00, m01, m10, m11);
      y00 = m00; y01 = m01; y10 = m10; y11 = m11;
    }
  }

  // ---- cross-wave stitch (single barrier) ----
  if (lane == 63) { smp[wv][0] = x00; smp[wv][1] = x01; smp[wv][2] = x10; smp[wv][3] = x11; }
  if (lane == 0)  { sms[wv][0] = y00; sms[wv][1] = y01; sms[wv][2] = y10; sms[wv][3] = y11; }
  __syncthreads();

  // fhead = W_{wv-1} (x) ... (x) W_0 (x) 0vec   (broadcast LDS reads)
  float fh0 = 0.f, fh1 = 0.f;
  for (int k = 0; k < wv; ++k) {
    float m0 = fmaxf(smp[k][0] + fh0, smp[k][1] + fh1);
    float m1 = fmaxf(smp[k][2] + fh0, smp[k][3] + fh1);
    fh0 = m0; fh1 = m1;
  }
  // wtail = V_{wv+1} (x) ... (x) V_{NWAVE-1} (x) w_base
  float wt0 = wb, wt1 = wb;
  for (int k = NWAVE - 1; k > wv; --k) {
    float m0 = fmaxf(sms[k][0] + wt0, sms[k][1] + wt1);
    float m1 = fmaxf(sms[k][2] + wt0, sms[k][3] + wt1);
    wt0 = m0; wt1 = m1;
  }

  // fwd boundary: z_c = X_c (x) fhead; f_in = z_{c-1}
  float z0 = fmaxf(x00 + fh0, x01 + fh1);
  float z1 = fmaxf(x10 + fh0, x11 + fh1);
  float zp0 = __shfl_up(z0, 1), zp1 = __shfl_up(z1, 1);
  float fi0 = (lane == 0) ? fh0 : zp0;
  float fi1 = (lane == 0) ? fh1 : zp1;

  // bwd boundary: y_c = Y_c (x) wtail = w_{c-1}; w_c from lane+1
  float yv0 = fmaxf(y00 + wt0, y01 + wt1);
  float yv1 = fmaxf(y10 + wt0, y11 + wt1);
  float yn0 = __shfl_down(yv0, 1), yn1 = __shfl_down(yv1, 1);
  float wc0 = (lane == 63) ? wt0 : yn0;
  float wc1 = (lane == 63) ? wt1 : yn1;
  float g0 = fmaxf(q + wc0, -q + wc1);
  float g1 = fmaxf(-q + wc0, q + wc1);

  // ---- in-chunk backward sweep (4 steps) ----
  float b0[CHUNK], b1[CHUNK];
  b0[CHUNK - 1] = g0; b1[CHUNK - 1] = g1;
#pragma unroll
  for (int i = CHUNK - 1; i > 0; --i) {
    float a0 = b0[i] - u[i], a1 = b1[i] + u[i];
    b0[i - 1] = fmaxf(a0 + q, a1 - q);
    b1[i - 1] = fmaxf(a0 - q, a1 + q);
  }

  // ---- forward sweep + beliefs (exp2); one dense 16B store per plane ----
  float fw0 = fi0, fw1 = fi1;
  vf4 p0, p1;
#pragma unroll
  for (int i = 0; i < CHUNK; ++i) {
    float ui = u[i];
    p0[i] = __builtin_amdgcn_exp2f(-ui + fw0 + b0[i]);
    p1[i] = __builtin_amdgcn_exp2f( ui + fw1 + b1[i]);
    float a0 = fw0 - ui, a1 = fw1 + ui;
    fw0 = fmaxf(a0 + q, a1 - q);
    fw1 = fmaxf(a0 - q, a1 + q);
  }
  float* outp = out + (size_t)row * (2 * LENGTH) + t0;
  *reinterpret_cast<vf4*>(outp)          = p0;   // wave: 1 KB contiguous
  *reinterpret_cast<vf4*>(outp + LENGTH) = p1;   // wave: 1 KB contiguous
}

extern "C" void kernel_launch(void* const* d_in, const int* in_sizes, int n_in,
                              void* d_out, int out_size, void* d_ws, size_t ws_size,
                              hipStream_t stream) {
  const float* jp  = (const float*)d_in[0];   // scalar j
  const float* bp  = (const float*)d_in[1];   // b[2]
  const int*   obs = (const int*)d_in[2];     // [BATCH, LENGTH] int32
  float* out = (float*)d_out;                 // [BATCH, 2, LENGTH] fp32

  chain_bp_kernel<<<BATCH, NTHR, 0, stream>>>(jp, bp, obs, out);
}

// Round 11
// 189.754 us; speedup vs baseline: 1.1428x; 1.0293x over previous
//
#include <hip/hip_runtime.h>
#include <math.h>

#define LENGTH 4096
#define BATCH  4096
#define CHUNK  8       // timesteps per thread
#define NTHR   512     // threads per block; NTHR*CHUNK == LENGTH (one block per row)
#define NWAVE  (NTHR / 64)

typedef float vf4 __attribute__((ext_vector_type(4)));
typedef _Float16 h2 __attribute__((ext_vector_type(2)));

__device__ __forceinline__ h2 h2max(h2 a, h2 b) { return __builtin_elementwise_max(a, b); }
__device__ __forceinline__ h2 bclo(h2 a) { return (h2){a[0], a[0]}; }
__device__ __forceinline__ h2 bchi(h2 a) { return (h2){a[1], a[1]}; }
__device__ __forceinline__ float h2f(h2 a) { return __builtin_bit_cast(float, a); }
__device__ __forceinline__ h2 f2h(float a) { return __builtin_bit_cast(h2, a); }

// max-plus 2x2 compose (fp32): D = A (x) B, D[k][l] = max_m A[k][m] + B[m][l]
__device__ __forceinline__ void mp_compose(
    float a00, float a01, float a10, float a11,
    float b00, float b01, float b10, float b11,
    float& d00, float& d01, float& d10, float& d11) {
  d00 = fmaxf(a00 + b00, a01 + b10);
  d01 = fmaxf(a00 + b01, a01 + b11);
  d10 = fmaxf(a10 + b00, a11 + b10);
  d11 = fmaxf(a10 + b01, a11 + b11);
}

// F <- (S (x) D_u) (x) F
__device__ __forceinline__ void mp_step(
    float& f00, float& f01, float& f10, float& f11, float ui, float q) {
  float a0l0 = f00 - ui, a1l0 = f10 + ui;
  float a0l1 = f01 - ui, a1l1 = f11 + ui;
  float n00 = fmaxf(a0l0 + q, a1l0 - q);
  float n10 = fmaxf(a0l0 - q, a1l0 + q);
  float n01 = fmaxf(a0l1 + q, a1l1 - q);
  float n11 = fmaxf(a0l1 - q, a1l1 + q);
  f00 = n00; f01 = n01; f10 = n10; f11 = n11;
}

__global__ __launch_bounds__(NTHR, 8) void chain_bp_kernel(
    const float* __restrict__ jp, const float* __restrict__ bp,
    const int* __restrict__ obs, float* __restrict__ out) {
  const int row  = blockIdx.x;
  const int tid  = threadIdx.x;
  const int lane = tid & 63;
  const int wv   = tid >> 6;

  // Potentials pre-scaled by log2(e): epilogue uses raw v_exp_f32 (2^x).
  const float LOG2E = 1.44269504088896f;
  const float j  = jp[0];
  const float q  = 0.25f * j * LOG2E;
  const float u0 = 0.5f * bp[0] * LOG2E;
  const float u1 = 0.5f * bp[1] * LOG2E;
  const float wb = -fabsf(q);              // 0vec == S (x) (wb,wb)

  __shared__ vf4 lut4s[16];
  __shared__ vf4 lut8[256];
  __shared__ float smp[NWAVE][4];  // per-wave full prefix matrix
  __shared__ float sms[NWAVE][4];  // per-wave full suffix matrix

  // ---- load this thread's 8 observations (two int4) ----
  const int t0 = tid * CHUNK;
  const int4* op = reinterpret_cast<const int4*>(obs + (size_t)row * LENGTH + t0);
  int4 o0 = op[0], o1 = op[1];
  float u[CHUNK];
  u[0]=o0.x?u1:u0; u[1]=o0.y?u1:u0; u[2]=o0.z?u1:u0; u[3]=o0.w?u1:u0;
  u[4]=o1.x?u1:u0; u[5]=o1.y?u1:u0; u[6]=o1.z?u1:u0; u[7]=o1.w?u1:u0;
  int idx = o0.x | (o0.y<<1) | (o0.z<<2) | (o0.w<<3)
          | (o1.x<<4) | (o1.y<<5) | (o1.z<<6) | (o1.w<<7);

  // ---- build 4-bit LUT (16 threads), then 8-bit LUT (256 threads) ----
  if (tid < 16) {
    float ua = (tid & 1) ? u1 : u0;
    float f00 = -ua + q, f01 = ua - q, f10 = -ua - q, f11 = ua + q;
#pragma unroll
    for (int k = 1; k < 4; ++k)
      mp_step(f00, f01, f10, f11, ((tid >> k) & 1) ? u1 : u0, q);
    lut4s[tid] = (vf4){f00, f01, f10, f11};
  }
  __syncthreads();
  if (tid < 256) {
    vf4 a = lut4s[tid >> 4], c = lut4s[tid & 15];
    float d00, d01, d10, d11;
    mp_compose(a[0], a[1], a[2], a[3], c[0], c[1], c[2], c[3], d00, d01, d10, d11);
    lut8[tid] = (vf4){d00, d01, d10, d11};
  }
  __syncthreads();

  vf4 Fm = lut8[idx];
  float f00 = Fm[0], f01 = Fm[1], f10 = Fm[2], f11 = Fm[3];

  // ---- split: fp32 level (m11) + normalized fp16x2 remainder ----
  float lvl = f11;
  h2 xr0 = { (_Float16)(f00 - lvl), (_Float16)(f01 - lvl) };
  h2 xr1 = { (_Float16)(f10 - lvl), (_Float16)(f11 - lvl) };
  float xl = lvl;
  h2 yr0 = { (_Float16)(f00 - lvl), (_Float16)(f10 - lvl) };   // transpose
  h2 yr1 = { (_Float16)(f01 - lvl), (_Float16)(f11 - lvl) };
  float yl = lvl;

  // ---- interleaved wave scans, packed fp16 + fp32 level (3 bperm each) ----
#pragma unroll
  for (int d = 1; d < 64; d <<= 1) {
    h2 pxr0 = f2h(__shfl_up(h2f(xr0), d));
    h2 pxr1 = f2h(__shfl_up(h2f(xr1), d));
    float pxl = __shfl_up(xl, d);
    h2 qyr0 = f2h(__shfl_down(h2f(yr0), d));
    h2 qyr1 = f2h(__shfl_down(h2f(yr1), d));
    float qyl = __shfl_down(yl, d);
    if (lane >= d) {
      h2 n0 = h2max(bclo(xr0) + pxr0, bchi(xr0) + pxr1);
      h2 n1 = h2max(bclo(xr1) + pxr0, bchi(xr1) + pxr1);
      xr0 = n0; xr1 = n1; xl += pxl;
    }
    if (lane + d < 64) {
      h2 n0 = h2max(bclo(yr0) + qyr0, bchi(yr0) + qyr1);
      h2 n1 = h2max(bclo(yr1) + qyr0, bchi(yr1) + qyr1);
      yr0 = n0; yr1 = n1; yl += qyl;
    }
  }
  // reconstruct fp32 scan results
  float x00 = (float)xr0[0] + xl, x01 = (float)xr0[1] + xl;
  float x10 = (float)xr1[0] + xl, x11 = (float)xr1[1] + xl;
  float y00 = (float)yr0[0] + yl, y01 = (float)yr0[1] + yl;
  float y10 = (float)yr1[0] + yl, y11 = (float)yr1[1] + yl;

  // ---- cross-wave stitch (fp32) ----
  if (lane == 63) { smp[wv][0] = x00; smp[wv][1] = x01; smp[wv][2] = x10; smp[wv][3] = x11; }
  if (lane == 0)  { sms[wv][0] = y00; sms[wv][1] = y01; sms[wv][2] = y10; sms[wv][3] = y11; }
  __syncthreads();

  float fh0 = 0.f, fh1 = 0.f;
  for (int k = 0; k < wv; ++k) {
    float m0 = fmaxf(smp[k][0] + fh0, smp[k][1] + fh1);
    float m1 = fmaxf(smp[k][2] + fh0, smp[k][3] + fh1);
    fh0 = m0; fh1 = m1;
  }
  float wt0 = wb, wt1 = wb;
  for (int k = NWAVE - 1; k > wv; --k) {
    float m0 = fmaxf(sms[k][0] + wt0, sms[k][1] + wt1);
    float m1 = fmaxf(sms[k][2] + wt0, sms[k][3] + wt1);
    wt0 = m0; wt1 = m1;
  }

  // fwd boundary: z_c = X_c (x) fhead; f_in = z_{c-1}
  float z0 = fmaxf(x00 + fh0, x01 + fh1);
  float z1 = fmaxf(x10 + fh0, x11 + fh1);
  float zp0 = __shfl_up(z0, 1), zp1 = __shfl_up(z1, 1);
  float fi0 = (lane == 0) ? fh0 : zp0;
  float fi1 = (lane == 0) ? fh1 : zp1;

  // bwd boundary: y_c = Y_c (x) wtail = w_{c-1}; w_c from lane+1
  float yv0 = fmaxf(y00 + wt0, y01 + wt1);
  float yv1 = fmaxf(y10 + wt0, y11 + wt1);
  float yn0 = __shfl_down(yv0, 1), yn1 = __shfl_down(yv1, 1);
  float wc0 = (lane == 63) ? wt0 : yn0;
  float wc1 = (lane == 63) ? wt1 : yn1;
  float g0 = fmaxf(q + wc0, -q + wc1);
  float g1 = fmaxf(-q + wc0, q + wc1);

  // ---- in-chunk backward sweep ----
  float b0[CHUNK], b1[CHUNK];
  b0[CHUNK - 1] = g0; b1[CHUNK - 1] = g1;
#pragma unroll
  for (int i = CHUNK - 1; i > 0; --i) {
    float a0 = b0[i] - u[i], a1 = b1[i] + u[i];
    b0[i - 1] = fmaxf(a0 + q, a1 - q);
    b1[i - 1] = fmaxf(a0 - q, a1 + q);
  }

  // ---- forward sweep + beliefs (exp2); 4 adjacent 16B stores ----
  float fw0 = fi0, fw1 = fi1;
  vf4 p0lo, p0hi, p1lo, p1hi;
#pragma unroll
  for (int i = 0; i < CHUNK; ++i) {
    float ui = u[i];
    float e0 = __builtin_amdgcn_exp2f(-ui + fw0 + b0[i]);
    float e1 = __builtin_amdgcn_exp2f( ui + fw1 + b1[i]);
    if (i < 4) { p0lo[i] = e0; p1lo[i] = e1; }
    else       { p0hi[i - 4] = e0; p1hi[i - 4] = e1; }
    float a0 = fw0 - ui, a1 = fw1 + ui;
    fw0 = fmaxf(a0 + q, a1 - q);
    fw1 = fmaxf(a0 - q, a1 + q);
  }
  float* outp = out + (size_t)row * (2 * LENGTH) + t0;
  *reinterpret_cast<vf4*>(outp)              = p0lo;
  *reinterpret_cast<vf4*>(outp + 4)          = p0hi;
  *reinterpret_cast<vf4*>(outp + LENGTH)     = p1lo;
  *reinterpret_cast<vf4*>(outp + LENGTH + 4) = p1hi;
}

extern "C" void kernel_launch(void* const* d_in, const int* in_sizes, int n_in,
                              void* d_out, int out_size, void* d_ws, size_t ws_size,
                              hipStream_t stream) {
  const float* jp  = (const float*)d_in[0];   // scalar j
  const float* bp  = (const float*)d_in[1];   // b[2]
  const int*   obs = (const int*)d_in[2];     // [BATCH, LENGTH] int32
  float* out = (float*)d_out;                 // [BATCH, 2, LENGTH] fp32

  chain_bp_kernel<<<BATCH, NTHR, 0, stream>>>(jp, bp, obs, out);
}